// Round 13
// baseline (180.454 us; speedup 1.0000x reference)
//
#include <hip/hip_runtime.h>

// RNN_53214644797476: out = tanh(X @ W^T + hs @ H^T), hs never updated.
// => one GEMM [32768,1024]x[1024,1024]^T + tiny h_term + tanh epilogue.
// Round 13: faithful port of the verified 256^2 8-phase template (m201):
// BK=64, 8 waves (2Mx4N), 512 thr, 128 KiB LDS (2buf x 2half x {A,B}),
// 8 phases per 2 K-tiles, one half-tile stage per phase, vmcnt(4) only at
// phases 4/8 (loads live ~a full K-tile), setprio around each 16-MFMA
// cluster. Stage->consume map WAR-verified per phase. Prep = R7's 8-slot
// pre-swizzle (0 bank conflicts, bit-identical output). Grid 512, XCD-
// bijective swizzle, A-panel sharers co-XCD. 1 block/CU (like m201).

typedef __bf16 bf16x8 __attribute__((ext_vector_type(8)));
typedef float f32x4 __attribute__((ext_vector_type(4)));
typedef unsigned short us4 __attribute__((ext_vector_type(4)));

constexpr int M_TOT = 32768;  // SEQ*BATCH
constexpr int K_D = 1024;
constexpr int N_D = 1024;
constexpr int BM = 256, BN = 256, BK = 64;
constexpr int NKT = K_D / BK;   // 16 K-tiles
constexpr int NIT = NKT / 2;    // 8 loop iterations (2 K-tiles each)
constexpr int HALF = 128 * 64;  // ushorts per half-tile (16 KiB)

__device__ __forceinline__ void async16(const void* g, void* l) {
  __builtin_amdgcn_global_load_lds(
      (const __attribute__((address_space(1))) unsigned int*)g,
      (__attribute__((address_space(3))) unsigned int*)l, 16, 0, 0);
}

__device__ __forceinline__ unsigned short f2bf(float f) {
  unsigned int u = __float_as_uint(f);
  u += 0x7FFFu + ((u >> 16) & 1u);  // round-to-nearest-even
  return (unsigned short)(u >> 16);
}

// ---- merged prep (R7 version: 8-slot pre-swizzle) ----
// blocks [0, XBLK): X cvt; [XBLK,+WBLK): W cvt; [XBLK+WBLK,+HBLK): h_term.
// 16B slot st of row stored at sd = (st&~7) | ((st&7) ^ (row&7)).
constexpr int PREP_XBLK = M_TOT * K_D / 4 / 256;  // 32768
constexpr int PREP_WBLK = N_D * K_D / 4 / 256;    // 1024
constexpr int PREP_HBLK = 1024;
constexpr int PREP_GRID = PREP_XBLK + PREP_WBLK + PREP_HBLK;

__global__ __launch_bounds__(256) void prep_kernel(
    const float* __restrict__ X, unsigned short* __restrict__ Xbf,
    const float* __restrict__ W, unsigned short* __restrict__ Wbf,
    const float* __restrict__ hs, const float* __restrict__ Hm,
    float* __restrict__ ht) {
  __shared__ float4 Hrow4[256];
  const int b = blockIdx.x;
  const int tid = threadIdx.x;

  if (b < PREP_XBLK + PREP_WBLK) {
    const float* in = (b < PREP_XBLK) ? X : W;
    unsigned short* out = (b < PREP_XBLK) ? Xbf : Wbf;
    int j = (b < PREP_XBLK) ? (b * 256 + tid) : ((b - PREP_XBLK) * 256 + tid);
    // j indexes half-slots (4 floats each).
    int slot = j >> 1, half = j & 1;
    int row = slot >> 7, st = slot & 127;
    int sd = (st & ~7) | ((st & 7) ^ (row & 7));
    float4 a = *reinterpret_cast<const float4*>(in + (size_t)j * 4);
    us4 v;
    v[0] = f2bf(a.x); v[1] = f2bf(a.y); v[2] = f2bf(a.z); v[3] = f2bf(a.w);
    *reinterpret_cast<us4*>(out + (size_t)row * 1024 + sd * 8 + half * 4) = v;
  } else {
    // h_term[bb][h] = sum_k hs[bb][k] * Hm[h][k]
    int h = b - (PREP_XBLK + PREP_WBLK);
    Hrow4[tid] = reinterpret_cast<const float4*>(Hm + (size_t)h * 1024)[tid];
    __syncthreads();
    int w = tid >> 6, l = tid & 63;
#pragma unroll 2
    for (int bb = w * 16; bb < w * 16 + 16; ++bb) {
      const float4* hb4 = reinterpret_cast<const float4*>(hs + (size_t)bb * 1024);
      float s = 0.f;
#pragma unroll
      for (int p = 0; p < 4; ++p) {
        float4 x = hb4[l + p * 64];
        float4 y = Hrow4[l + p * 64];
        s += x.x * y.x + x.y * y.y + x.z * y.z + x.w * y.w;
      }
#pragma unroll
      for (int off = 32; off > 0; off >>= 1) s += __shfl_down(s, off, 64);
      if (l == 0) ht[bb * 1024 + h] = s;
    }
  }
}

// ---- main GEMM: 256x256 8-phase, C = tanh(A.B^T + ht[m%64][n]) ----
__global__ __launch_bounds__(512, 2) void gemm_tanh(
    const unsigned short* __restrict__ A, const unsigned short* __restrict__ B,
    const float* __restrict__ ht, float* __restrict__ out0,
    float* __restrict__ out1) {
  __shared__ unsigned short As[2][2][HALF];  // [buf][half] 64 KiB
  __shared__ unsigned short Bs[2][2][HALF];  // 64 KiB

  // XCD-bijective swizzle (nwg = 512 % 8 == 0); 4 bn-sharers of an A-panel
  // are consecutive within an XCD chunk.
  int bid = blockIdx.x;
  int swz = (bid & 7) * 64 + (bid >> 3);
  int bm = swz >> 2;  // 0..127
  int bn = swz & 3;   // 0..3

  int tid = threadIdx.x;
  int lane = tid & 63, wid = tid >> 6;
  int wr = wid >> 2, wc = wid & 3;  // 2M x 4N waves; wave tile 128x64
  int fr = lane & 15, kq = lane >> 4;

  const int arow = bm * BM;  // A panel base row
  const int brow = bn * BN;  // B panel base row

  f32x4 acc[8][4] = {};
  bf16x8 bg[4][2];

#define STG(g_, rowbase_, ks_, lds_)                                       \
  {                                                                        \
    _Pragma("unroll") for (int i_ = 0; i_ < 2; ++i_) {                     \
      int c_ = tid + i_ * 512;                                             \
      async16((g_) + (size_t)((rowbase_) + (c_ >> 3)) * 1024 + (ks_) +     \
                  (c_ & 7) * 8,                                            \
              (lds_) + c_ * 8);                                            \
    }                                                                      \
  }

#define LOAD_BG(bi_)                                                       \
  {                                                                        \
    _Pragma("unroll") for (int ni_ = 0; ni_ < 4; ++ni_)                    \
        _Pragma("unroll") for (int kk_ = 0; kk_ < 2; ++kk_) {              \
      int rb_ = (wc & 1) * 64 + ni_ * 16 + fr;                             \
      bg[ni_][kk_] = *reinterpret_cast<const bf16x8*>(                     \
          &Bs[bi_][wc >> 1][rb_ * 64 + ((kk_ * 4 + kq) ^ (rb_ & 7)) * 8]); \
    }                                                                      \
  }

#define LOAD_AF(bi_, q_)                                                   \
  {                                                                        \
    _Pragma("unroll") for (int dm_ = 0; dm_ < 2; ++dm_)                    \
        _Pragma("unroll") for (int kk_ = 0; kk_ < 2; ++kk_) {              \
      int ra_ = ((q_) * 2 + dm_) * 16 + fr;                                \
      af[dm_][kk_] = *reinterpret_cast<const bf16x8*>(                     \
          &As[bi_][wr][ra_ * 64 + ((kk_ * 4 + kq) ^ (ra_ & 7)) * 8]);      \
    }                                                                      \
  }

#define MFMA_Q(q_)                                                         \
  {                                                                        \
    __builtin_amdgcn_s_setprio(1);                                         \
    _Pragma("unroll") for (int dm_ = 0; dm_ < 2; ++dm_)                    \
        _Pragma("unroll") for (int ni_ = 0; ni_ < 4; ++ni_)                \
            _Pragma("unroll") for (int kk_ = 0; kk_ < 2; ++kk_)            \
                acc[(q_) * 2 + dm_][ni_] =                                 \
        __builtin_amdgcn_mfma_f32_16x16x32_bf16(                           \
            af[dm_][kk_], bg[ni_][kk_], acc[(q_) * 2 + dm_][ni_], 0, 0, 0);\
    __builtin_amdgcn_s_setprio(0);                                         \
  }

#define BAR() __builtin_amdgcn_s_barrier()

  // Prologue: A(0),B(0) -> buf0; B(1) -> buf1.B. 12 loads; drain first 8.
  STG(A, arow + 0,   0, &As[0][0][0]);
  STG(A, arow + 128, 0, &As[0][1][0]);
  STG(B, brow + 0,   0, &Bs[0][0][0]);
  STG(B, brow + 128, 0, &Bs[0][1][0]);
  STG(B, brow + 0,   BK, &Bs[1][0][0]);
  STG(B, brow + 128, BK, &Bs[1][1][0]);
  asm volatile("s_waitcnt vmcnt(4)" ::: "memory");
  BAR();

  for (int j = 0; j < NIT; ++j) {
    const int kt1 = 2 * j + 1;     // second K-tile of this iter (buf1)
    const int kn = 2 * j + 2;      // next pair's first K-tile
    const bool nl = (j < NIT - 1); // not last

    // ---- phases 1-4: K-tile 2j from buf0 ----
    {  // phase 1: q0; stage A0(kt1)->buf1.A0 (free since prev iter)
      bf16x8 af[2][2];
      LOAD_BG(0); LOAD_AF(0, 0);
      STG(A, arow + 0, kt1 * BK, &As[1][0][0]);
      BAR(); MFMA_Q(0); BAR();
    }
    {  // phase 2: q1; stage A1(kt1)->buf1.A1
      bf16x8 af[2][2];
      LOAD_AF(0, 1);
      STG(A, arow + 128, kt1 * BK, &As[1][1][0]);
      BAR(); MFMA_Q(1); BAR();
    }
    {  // phase 3: q2; stage B0(kn)->buf0.B0 (B(2j) reads done at phase 1)
      bf16x8 af[2][2];
      LOAD_AF(0, 2);
      if (nl) STG(B, brow + 0, kn * BK, &Bs[0][0][0]);
      BAR(); MFMA_Q(2); BAR();
    }
    {  // phase 4: q3; stage B1(kn)->buf0.B1; counted drain for phases 5-8
      bf16x8 af[2][2];
      LOAD_AF(0, 3);
      if (nl) STG(B, brow + 128, kn * BK, &Bs[0][1][0]);
      BAR(); MFMA_Q(3);
      if (nl)
        asm volatile("s_waitcnt vmcnt(4)" ::: "memory");  // A(kt1),B(kt1) in
      else
        asm volatile("s_waitcnt vmcnt(0)" ::: "memory");
      BAR();
    }
    // ---- phases 5-8: K-tile kt1 from buf1 ----
    {  // phase 5: q0; stage A0(kn)->buf0.A0 (A(2j) reads done at phase 4)
      bf16x8 af[2][2];
      LOAD_BG(1); LOAD_AF(1, 0);
      if (nl) STG(A, arow + 0, kn * BK, &As[0][0][0]);
      BAR(); MFMA_Q(0); BAR();
    }
    {  // phase 6: q1; stage A1(kn)->buf0.A1
      bf16x8 af[2][2];
      LOAD_AF(1, 1);
      if (nl) STG(A, arow + 128, kn * BK, &As[0][1][0]);
      BAR(); MFMA_Q(1); BAR();
    }
    {  // phase 7: q2; stage B0(kn+1)->buf1.B0 (B(kt1) reads done at phase 5)
      bf16x8 af[2][2];
      LOAD_AF(1, 2);
      if (nl) STG(B, brow + 0, (kn + 1) * BK, &Bs[1][0][0]);
      BAR(); MFMA_Q(2); BAR();
    }
    {  // phase 8: q3; stage B1(kn+1)->buf1.B1; counted drain for next iter
      bf16x8 af[2][2];
      LOAD_AF(1, 3);
      if (nl) STG(B, brow + 128, (kn + 1) * BK, &Bs[1][1][0]);
      BAR(); MFMA_Q(3);
      if (nl) asm volatile("s_waitcnt vmcnt(4)" ::: "memory");  // A,B(kn) in
      BAR();
    }
  }

  // Epilogue: y = tanh(acc + ht[m%64][n]); out0 always, out1 for last 64 rows.
  const int nbase = brow + wc * 64;
  const int mbase = arow + wr * 128;
#pragma unroll
  for (int mi = 0; mi < 8; ++mi) {
#pragma unroll
    for (int r = 0; r < 4; ++r) {
      int mloc = mi * 16 + kq * 4 + r;     // 0..127 within wave half
      size_t m = (size_t)mbase + mloc;
      int b = mloc & 63;                    // (mbase multiple of 64)
#pragma unroll
      for (int ni = 0; ni < 4; ++ni) {
        int n = nbase + ni * 16 + fr;
        float x = acc[mi][ni][r] + ht[b * 1024 + n];
        float e = __expf(2.0f * x);
        float y = 1.0f - 2.0f / (e + 1.0f);  // tanh(x), safe at +-inf
        out0[m * 1024 + n] = y;
        if (m >= (size_t)(M_TOT - 64))
          out1[(m - (M_TOT - 64)) * 1024 + n] = y;
      }
    }
  }
#undef STG
#undef LOAD_BG
#undef LOAD_AF
#undef MFMA_Q
#undef BAR
}

extern "C" void kernel_launch(void* const* d_in, const int* in_sizes, int n_in,
                              void* d_out, int out_size, void* d_ws,
                              size_t ws_size, hipStream_t stream) {
  (void)in_sizes; (void)n_in; (void)out_size; (void)ws_size;
  const float* X  = (const float*)d_in[0];  // [512,64,1024] = [32768,1024]
  const float* hs = (const float*)d_in[1];  // [64,1024]
  const float* W  = (const float*)d_in[2];  // [1024,1024]
  const float* Hm = (const float*)d_in[3];  // [1024,1024]
  float* out0 = (float*)d_out;               // [32768,1024]
  float* out1 = out0 + (size_t)M_TOT * N_D;  // [64,1024]

  // ws layout: Xbf (64 MiB) | Wbf (2 MiB) | hterm (256 KiB)
  unsigned short* Xbf = (unsigned short*)d_ws;
  unsigned short* Wbf = Xbf + (size_t)M_TOT * K_D;
  float* hterm = (float*)(Wbf + (size_t)N_D * K_D);

  prep_kernel<<<PREP_GRID, 256, 0, stream>>>(X, Xbf, W, Wbf, hs, Hm, hterm);
  gemm_tanh<<<(M_TOT / BM) * (N_D / BN), 512, 0, stream>>>(Xbf, Wbf, hterm,
                                                           out0, out1);
}

// Round 14
// 153.452 us; speedup vs baseline: 1.1760x; 1.1760x over previous
//
#include <hip/hip_runtime.h>

// RNN_53214644797476: out = tanh(X @ W^T + hs @ H^T), hs never updated.
// => one GEMM [32768,1024]x[1024,1024]^T + tiny h_term + tanh epilogue.
// Round 14 (final): R12's measured-best GEMM verbatim (256x128 tile, 512
// thr, 8 waves 64x64, BK=32, 3-buffer 2-deep counted-vmcnt, 72 KB LDS,
// 2 blk/CU x 8 waves = 16 waves/CU, pre-swizzled inputs -> 0 conflicts,
// XCD-bijective swizzle). Prep tightened toward its BW floor: one 16B
// slot per thread = 2 independent float4 loads + 1 ushort8 store (2x MLP,
// half the store instructions vs R6's 8B-store version).
// History: 2-phase ceiling ~650 TF confirmed via R1/R6/R8/R9/R12; 8-phase
// falsified at this shape (R2/R13: K=1024 -> 16 K-tiles, no steady state);
// fusion falsified (R3/R11); BK=64 L2-thrash (R7); B-direct gather (R10).

typedef __bf16 bf16x8 __attribute__((ext_vector_type(8)));
typedef float f32x4 __attribute__((ext_vector_type(4)));
typedef unsigned short us8 __attribute__((ext_vector_type(8)));

constexpr int M_TOT = 32768;  // SEQ*BATCH
constexpr int K_D = 1024;
constexpr int N_D = 1024;
constexpr int BM = 256, BN = 128, BKT = 32;
constexpr int NTK = K_D / BKT;  // 32 K-tiles
constexpr int ATILE = BM * BKT; // 8192 ushorts = 16 KiB
constexpr int BTILE = BN * BKT; // 4096 ushorts = 8 KiB

__device__ __forceinline__ void async16(const void* g, void* l) {
  __builtin_amdgcn_global_load_lds(
      (const __attribute__((address_space(1))) unsigned int*)g,
      (__attribute__((address_space(3))) unsigned int*)l, 16, 0, 0);
}

__device__ __forceinline__ unsigned short f2bf(float f) {
  unsigned int u = __float_as_uint(f);
  u += 0x7FFFu + ((u >> 16) & 1u);  // round-to-nearest-even
  return (unsigned short)(u >> 16);
}

// ---- merged prep ----
// blocks [0, XBLK): X cvt, one 16B slot per thread (2 float4 loads);
// [XBLK,+WBLK): W cvt, same; [XBLK+WBLK,+HBLK): h_term, one block per h.
// Slot pre-swizzle (matches gemm read XOR): 16B slot st of row stored at
// sd = (st&~3) | ((st&3) ^ ((row>>1)&3)).
constexpr int PREP_XBLK = M_TOT * K_D / 8 / 256;  // 16384
constexpr int PREP_WBLK = N_D * K_D / 8 / 256;    // 512
constexpr int PREP_HBLK = 1024;
constexpr int PREP_GRID = PREP_XBLK + PREP_WBLK + PREP_HBLK;

__global__ __launch_bounds__(256) void prep_kernel(
    const float* __restrict__ X, unsigned short* __restrict__ Xbf,
    const float* __restrict__ W, unsigned short* __restrict__ Wbf,
    const float* __restrict__ hs, const float* __restrict__ Hm,
    float* __restrict__ ht) {
  __shared__ float4 Hrow4[256];
  const int b = blockIdx.x;
  const int tid = threadIdx.x;

  if (b < PREP_XBLK + PREP_WBLK) {
    const float* in = (b < PREP_XBLK) ? X : W;
    unsigned short* out = (b < PREP_XBLK) ? Xbf : Wbf;
    int j = (b < PREP_XBLK) ? (b * 256 + tid) : ((b - PREP_XBLK) * 256 + tid);
    // j indexes full 16B slots (8 floats each).
    int row = j >> 7, st = j & 127;
    int sd = (st & ~3) | ((st & 3) ^ ((row >> 1) & 3));
    const float4* p = reinterpret_cast<const float4*>(in + (size_t)j * 8);
    float4 a = p[0], c = p[1];  // 2 independent loads (MLP=2)
    us8 v;
    v[0] = f2bf(a.x); v[1] = f2bf(a.y); v[2] = f2bf(a.z); v[3] = f2bf(a.w);
    v[4] = f2bf(c.x); v[5] = f2bf(c.y); v[6] = f2bf(c.z); v[7] = f2bf(c.w);
    *reinterpret_cast<us8*>(out + (size_t)row * 1024 + sd * 8) = v;
  } else {
    // h_term[bb][h] = sum_k hs[bb][k] * Hm[h][k]
    int h = b - (PREP_XBLK + PREP_WBLK);
    Hrow4[tid] = reinterpret_cast<const float4*>(Hm + (size_t)h * 1024)[tid];
    __syncthreads();
    int w = tid >> 6, l = tid & 63;
#pragma unroll 2
    for (int bb = w * 16; bb < w * 16 + 16; ++bb) {
      const float4* hb4 = reinterpret_cast<const float4*>(hs + (size_t)bb * 1024);
      float s = 0.f;
#pragma unroll
      for (int p = 0; p < 4; ++p) {
        float4 x = hb4[l + p * 64];
        float4 y = Hrow4[l + p * 64];
        s += x.x * y.x + x.y * y.y + x.z * y.z + x.w * y.w;
      }
#pragma unroll
      for (int off = 32; off > 0; off >>= 1) s += __shfl_down(s, off, 64);
      if (l == 0) ht[bb * 1024 + h] = s;
    }
  }
}

// ---- main GEMM (R12 verbatim): C = tanh(A.B^T + ht[m%64][n]) ----
// 256x128 tile, 8 waves (4x2) of 64x64, 3-buffer 2-deep counted-vmcnt.
__global__ __launch_bounds__(512, 4) void gemm_tanh(
    const unsigned short* __restrict__ A, const unsigned short* __restrict__ B,
    const float* __restrict__ ht, float* __restrict__ out0,
    float* __restrict__ out1) {
  __shared__ unsigned short As[3][ATILE];  // 48 KiB
  __shared__ unsigned short Bs[3][BTILE];  // 24 KiB

  // XCD-bijective swizzle (nwg = 1024 % 8 == 0); A-panel sharers co-XCD.
  int bid = blockIdx.x;
  int swz = (bid & 7) * 128 + (bid >> 3);
  int bm = swz >> 3;  // 0..127
  int bn = swz & 7;   // 0..7

  int tid = threadIdx.x;
  int lane = tid & 63, wid = tid >> 6;
  int wr = wid >> 1, wc = wid & 1;  // 4 x 2 waves, each 64x64 output
  int fr = lane & 15, kq = lane >> 4;

  // Staging: A = 1024 chunks (256 rows x 4 slots), B = 512 chunks.
  // Thread t stages A chunks t, t+512 and B chunk t. LDS dest linear;
  // global source pre-swizzled, so source addrs are linear too.
  int c1 = tid + 512;
  const unsigned short* gA0 =
      A + (size_t)(bm * BM + (tid >> 2)) * 1024 + (tid & 3) * 8;
  const unsigned short* gA1 =
      A + (size_t)(bm * BM + (c1 >> 2)) * 1024 + (tid & 3) * 8;
  const unsigned short* gB0 =
      B + (size_t)(bn * BN + (tid >> 2)) * 1024 + (tid & 3) * 8;

  f32x4 acc[4][4] = {};

#define STAGE(kt, buf)                                  \
  {                                                     \
    async16(gA0 + (kt) * BKT, &As[buf][tid * 8]);       \
    async16(gA1 + (kt) * BKT, &As[buf][c1 * 8]);        \
    async16(gB0 + (kt) * BKT, &Bs[buf][tid * 8]);       \
  }

  // Prologue: stage tiles 0 and 1; wait tile 0 only (counted); barrier.
  STAGE(0, 0);
  STAGE(1, 1);
  asm volatile("s_waitcnt vmcnt(3)" ::: "memory");
  __builtin_amdgcn_s_barrier();
  asm volatile("" ::: "memory");

  for (int kt = 0; kt < NTK; ++kt) {
    const int cur = kt % 3;
    // Stage 2 K-steps ahead; these loads fly across this iter's barrier.
    if (kt + 2 < NTK) STAGE(kt + 2, (kt + 2) % 3);

    bf16x8 af[4], bg[4];
#pragma unroll
    for (int mi = 0; mi < 4; ++mi) {
      int ra = wr * 64 + mi * 16 + fr;
      af[mi] = *reinterpret_cast<const bf16x8*>(
          &As[cur][ra * BKT + (kq ^ ((ra >> 1) & 3)) * 8]);
    }
#pragma unroll
    for (int ni = 0; ni < 4; ++ni) {
      int rb = wc * 64 + ni * 16 + fr;
      bg[ni] = *reinterpret_cast<const bf16x8*>(
          &Bs[cur][rb * BKT + (kq ^ ((rb >> 1) & 3)) * 8]);
    }
    __builtin_amdgcn_s_setprio(1);
#pragma unroll
    for (int mi = 0; mi < 4; ++mi)
#pragma unroll
      for (int ni = 0; ni < 4; ++ni)
        acc[mi][ni] = __builtin_amdgcn_mfma_f32_16x16x32_bf16(
            af[mi], bg[ni], acc[mi][ni], 0, 0, 0);
    __builtin_amdgcn_s_setprio(0);

    if (kt + 1 < NTK) {
      // Counted drain: ensure kt+1 resident (its 3 loads are the oldest),
      // keep kt+2's 3 loads in flight across the barrier.
      if (kt + 2 < NTK)
        asm volatile("s_waitcnt vmcnt(3)" ::: "memory");
      else
        asm volatile("s_waitcnt vmcnt(0)" ::: "memory");
      __builtin_amdgcn_s_barrier();
      asm volatile("" ::: "memory");
    }
  }

  // Epilogue: y = tanh(acc + ht[m%64][n]); out0 always, out1 for last 64 rows.
  const int nbase = bn * BN + wc * 64;
#pragma unroll
  for (int mi = 0; mi < 4; ++mi) {
#pragma unroll
    for (int r = 0; r < 4; ++r) {
      int mloc = wr * 64 + mi * 16 + kq * 4 + r;  // 0..255
      size_t m = (size_t)bm * BM + mloc;
      int b = mloc & 63;  // m % 64 (BM multiple of 64)
#pragma unroll
      for (int ni = 0; ni < 4; ++ni) {
        int n = nbase + ni * 16 + fr;
        float x = acc[mi][ni][r] + ht[b * 1024 + n];
        float e = __expf(2.0f * x);
        float y = 1.0f - 2.0f / (e + 1.0f);  // tanh(x), safe at +-inf
        out0[m * 1024 + n] = y;
        if (m >= (size_t)(M_TOT - 64))
          out1[(m - (M_TOT - 64)) * 1024 + n] = y;
      }
    }
  }
#undef STAGE
}

extern "C" void kernel_launch(void* const* d_in, const int* in_sizes, int n_in,
                              void* d_out, int out_size, void* d_ws,
                              size_t ws_size, hipStream_t stream) {
  (void)in_sizes; (void)n_in; (void)out_size; (void)ws_size;
  const float* X  = (const float*)d_in[0];  // [512,64,1024] = [32768,1024]
  const float* hs = (const float*)d_in[1];  // [64,1024]
  const float* W  = (const float*)d_in[2];  // [1024,1024]
  const float* Hm = (const float*)d_in[3];  // [1024,1024]
  float* out0 = (float*)d_out;               // [32768,1024]
  float* out1 = out0 + (size_t)M_TOT * N_D;  // [64,1024]

  // ws layout: Xbf (64 MiB) | Wbf (2 MiB) | hterm (256 KiB)
  unsigned short* Xbf = (unsigned short*)d_ws;
  unsigned short* Wbf = Xbf + (size_t)M_TOT * K_D;
  float* hterm = (float*)(Wbf + (size_t)N_D * K_D);

  prep_kernel<<<PREP_GRID, 256, 0, stream>>>(X, Xbf, W, Wbf, hs, Hm, hterm);
  gemm_tanh<<<(M_TOT / BM) * (N_D / BN), 512, 0, stream>>>(Xbf, Wbf, hterm,
                                                           out0, out1);
}

// Round 15
// 149.487 us; speedup vs baseline: 1.2071x; 1.0265x over previous
//
#include <hip/hip_runtime.h>

// RNN_53214644797476: out = tanh(X @ W^T + hs @ H^T), hs never updated.
// => one GEMM [32768,1024]x[1024,1024]^T + tiny h_term + tanh epilogue.
// Round 15 (closing): R14 verbatim + non-temporal cache hints:
//   - out0/out1 stores `nt` (write-once 131 MB no longer evicts Xbf/Wbf
//     panels from L2 during the GEMM)
//   - prep X/W loads `nt` (read-once f32 stream doesn't pollute L2)
// GEMM structure (measured best, 6-way confirmed ceiling ~650 TF):
// 256x128 tile, 512 thr, 8 waves 64x64, BK=32, 3-buffer 2-deep counted
// vmcnt, 72 KB LDS, 2 blk/CU x 8 waves = 16 waves/CU, pre-swizzled
// inputs -> 0 bank conflicts, XCD-bijective swizzle.
// Falsified on this shape: 8-phase (R2/R13), fusion (R3/R11), BK=64 (R7),
// B-direct (R10), 1-deep dbuf (R9), occupancy trades (R2/R4).

typedef __bf16 bf16x8 __attribute__((ext_vector_type(8)));
typedef float f32x4 __attribute__((ext_vector_type(4)));
typedef unsigned short us8 __attribute__((ext_vector_type(8)));

constexpr int M_TOT = 32768;  // SEQ*BATCH
constexpr int K_D = 1024;
constexpr int N_D = 1024;
constexpr int BM = 256, BN = 128, BKT = 32;
constexpr int NTK = K_D / BKT;  // 32 K-tiles
constexpr int ATILE = BM * BKT; // 8192 ushorts = 16 KiB
constexpr int BTILE = BN * BKT; // 4096 ushorts = 8 KiB

__device__ __forceinline__ void async16(const void* g, void* l) {
  __builtin_amdgcn_global_load_lds(
      (const __attribute__((address_space(1))) unsigned int*)g,
      (__attribute__((address_space(3))) unsigned int*)l, 16, 0, 0);
}

__device__ __forceinline__ unsigned short f2bf(float f) {
  unsigned int u = __float_as_uint(f);
  u += 0x7FFFu + ((u >> 16) & 1u);  // round-to-nearest-even
  return (unsigned short)(u >> 16);
}

// ---- merged prep ----
// blocks [0, XBLK): X cvt, one 16B slot per thread (2 float4 nt-loads);
// [XBLK,+WBLK): W cvt, same; [XBLK+WBLK,+HBLK): h_term, one block per h.
// Slot pre-swizzle (matches gemm read XOR): 16B slot st of row stored at
// sd = (st&~3) | ((st&3) ^ ((row>>1)&3)).
constexpr int PREP_XBLK = M_TOT * K_D / 8 / 256;  // 16384
constexpr int PREP_WBLK = N_D * K_D / 8 / 256;    // 512
constexpr int PREP_HBLK = 1024;
constexpr int PREP_GRID = PREP_XBLK + PREP_WBLK + PREP_HBLK;

__global__ __launch_bounds__(256) void prep_kernel(
    const float* __restrict__ X, unsigned short* __restrict__ Xbf,
    const float* __restrict__ W, unsigned short* __restrict__ Wbf,
    const float* __restrict__ hs, const float* __restrict__ Hm,
    float* __restrict__ ht) {
  __shared__ float4 Hrow4[256];
  const int b = blockIdx.x;
  const int tid = threadIdx.x;

  if (b < PREP_XBLK + PREP_WBLK) {
    const float* in = (b < PREP_XBLK) ? X : W;
    unsigned short* out = (b < PREP_XBLK) ? Xbf : Wbf;
    int j = (b < PREP_XBLK) ? (b * 256 + tid) : ((b - PREP_XBLK) * 256 + tid);
    // j indexes full 16B slots (8 floats each).
    int row = j >> 7, st = j & 127;
    int sd = (st & ~3) | ((st & 3) ^ ((row >> 1) & 3));
    const f32x4* p = reinterpret_cast<const f32x4*>(in + (size_t)j * 8);
    f32x4 a = __builtin_nontemporal_load(p);      // read-once stream: nt
    f32x4 c = __builtin_nontemporal_load(p + 1);  // 2 independent loads
    us8 v;
    v[0] = f2bf(a[0]); v[1] = f2bf(a[1]); v[2] = f2bf(a[2]); v[3] = f2bf(a[3]);
    v[4] = f2bf(c[0]); v[5] = f2bf(c[1]); v[6] = f2bf(c[2]); v[7] = f2bf(c[3]);
    *reinterpret_cast<us8*>(out + (size_t)row * 1024 + sd * 8) = v;
  } else {
    // h_term[bb][h] = sum_k hs[bb][k] * Hm[h][k]
    int h = b - (PREP_XBLK + PREP_WBLK);
    Hrow4[tid] = reinterpret_cast<const float4*>(Hm + (size_t)h * 1024)[tid];
    __syncthreads();
    int w = tid >> 6, l = tid & 63;
#pragma unroll 2
    for (int bb = w * 16; bb < w * 16 + 16; ++bb) {
      const float4* hb4 = reinterpret_cast<const float4*>(hs + (size_t)bb * 1024);
      float s = 0.f;
#pragma unroll
      for (int p = 0; p < 4; ++p) {
        float4 x = hb4[l + p * 64];
        float4 y = Hrow4[l + p * 64];
        s += x.x * y.x + x.y * y.y + x.z * y.z + x.w * y.w;
      }
#pragma unroll
      for (int off = 32; off > 0; off >>= 1) s += __shfl_down(s, off, 64);
      if (l == 0) ht[bb * 1024 + h] = s;
    }
  }
}

// ---- main GEMM (R12/R14 verbatim + nt epilogue stores) ----
// C = tanh(A.B^T + ht[m%64][n]); 256x128 tile, 8 waves (4x2) of 64x64,
// 3-buffer 2-deep counted-vmcnt.
__global__ __launch_bounds__(512, 4) void gemm_tanh(
    const unsigned short* __restrict__ A, const unsigned short* __restrict__ B,
    const float* __restrict__ ht, float* __restrict__ out0,
    float* __restrict__ out1) {
  __shared__ unsigned short As[3][ATILE];  // 48 KiB
  __shared__ unsigned short Bs[3][BTILE];  // 24 KiB

  // XCD-bijective swizzle (nwg = 1024 % 8 == 0); A-panel sharers co-XCD.
  int bid = blockIdx.x;
  int swz = (bid & 7) * 128 + (bid >> 3);
  int bm = swz >> 3;  // 0..127
  int bn = swz & 7;   // 0..7

  int tid = threadIdx.x;
  int lane = tid & 63, wid = tid >> 6;
  int wr = wid >> 1, wc = wid & 1;  // 4 x 2 waves, each 64x64 output
  int fr = lane & 15, kq = lane >> 4;

  // Staging: A = 1024 chunks (256 rows x 4 slots), B = 512 chunks.
  // Thread t stages A chunks t, t+512 and B chunk t. LDS dest linear;
  // global source pre-swizzled, so source addrs are linear too.
  int c1 = tid + 512;
  const unsigned short* gA0 =
      A + (size_t)(bm * BM + (tid >> 2)) * 1024 + (tid & 3) * 8;
  const unsigned short* gA1 =
      A + (size_t)(bm * BM + (c1 >> 2)) * 1024 + (tid & 3) * 8;
  const unsigned short* gB0 =
      B + (size_t)(bn * BN + (tid >> 2)) * 1024 + (tid & 3) * 8;

  f32x4 acc[4][4] = {};

#define STAGE(kt, buf)                                  \
  {                                                     \
    async16(gA0 + (kt) * BKT, &As[buf][tid * 8]);       \
    async16(gA1 + (kt) * BKT, &As[buf][c1 * 8]);        \
    async16(gB0 + (kt) * BKT, &Bs[buf][tid * 8]);       \
  }

  // Prologue: stage tiles 0 and 1; wait tile 0 only (counted); barrier.
  STAGE(0, 0);
  STAGE(1, 1);
  asm volatile("s_waitcnt vmcnt(3)" ::: "memory");
  __builtin_amdgcn_s_barrier();
  asm volatile("" ::: "memory");

  for (int kt = 0; kt < NTK; ++kt) {
    const int cur = kt % 3;
    // Stage 2 K-steps ahead; these loads fly across this iter's barrier.
    if (kt + 2 < NTK) STAGE(kt + 2, (kt + 2) % 3);

    bf16x8 af[4], bg[4];
#pragma unroll
    for (int mi = 0; mi < 4; ++mi) {
      int ra = wr * 64 + mi * 16 + fr;
      af[mi] = *reinterpret_cast<const bf16x8*>(
          &As[cur][ra * BKT + (kq ^ ((ra >> 1) & 3)) * 8]);
    }
#pragma unroll
    for (int ni = 0; ni < 4; ++ni) {
      int rb = wc * 64 + ni * 16 + fr;
      bg[ni] = *reinterpret_cast<const bf16x8*>(
          &Bs[cur][rb * BKT + (kq ^ ((rb >> 1) & 3)) * 8]);
    }
    __builtin_amdgcn_s_setprio(1);
#pragma unroll
    for (int mi = 0; mi < 4; ++mi)
#pragma unroll
      for (int ni = 0; ni < 4; ++ni)
        acc[mi][ni] = __builtin_amdgcn_mfma_f32_16x16x32_bf16(
            af[mi], bg[ni], acc[mi][ni], 0, 0, 0);
    __builtin_amdgcn_s_setprio(0);

    if (kt + 1 < NTK) {
      // Counted drain: ensure kt+1 resident (its 3 loads are the oldest),
      // keep kt+2's 3 loads in flight across the barrier.
      if (kt + 2 < NTK)
        asm volatile("s_waitcnt vmcnt(3)" ::: "memory");
      else
        asm volatile("s_waitcnt vmcnt(0)" ::: "memory");
      __builtin_amdgcn_s_barrier();
      asm volatile("" ::: "memory");
    }
  }

  // Epilogue: y = tanh(acc + ht[m%64][n]); out0 always, out1 for last 64
  // rows. Write-once output -> nt stores (don't evict A/B panels from L2).
  const int nbase = bn * BN + wc * 64;
#pragma unroll
  for (int mi = 0; mi < 4; ++mi) {
#pragma unroll
    for (int r = 0; r < 4; ++r) {
      int mloc = wr * 64 + mi * 16 + kq * 4 + r;  // 0..255
      size_t m = (size_t)bm * BM + mloc;
      int b = mloc & 63;  // m % 64 (BM multiple of 64)
#pragma unroll
      for (int ni = 0; ni < 4; ++ni) {
        int n = nbase + ni * 16 + fr;
        float x = acc[mi][ni][r] + ht[b * 1024 + n];
        float e = __expf(2.0f * x);
        float y = 1.0f - 2.0f / (e + 1.0f);  // tanh(x), safe at +-inf
        __builtin_nontemporal_store(y, &out0[m * 1024 + n]);
        if (m >= (size_t)(M_TOT - 64))
          __builtin_nontemporal_store(y, &out1[(m - (M_TOT - 64)) * 1024 + n]);
      }
    }
  }
#undef STAGE
}

extern "C" void kernel_launch(void* const* d_in, const int* in_sizes, int n_in,
                              void* d_out, int out_size, void* d_ws,
                              size_t ws_size, hipStream_t stream) {
  (void)in_sizes; (void)n_in; (void)out_size; (void)ws_size;
  const float* X  = (const float*)d_in[0];  // [512,64,1024] = [32768,1024]
  const float* hs = (const float*)d_in[1];  // [64,1024]
  const float* W  = (const float*)d_in[2];  // [1024,1024]
  const float* Hm = (const float*)d_in[3];  // [1024,1024]
  float* out0 = (float*)d_out;               // [32768,1024]
  float* out1 = out0 + (size_t)M_TOT * N_D;  // [64,1024]

  // ws layout: Xbf (64 MiB) | Wbf (2 MiB) | hterm (256 KiB)
  unsigned short* Xbf = (unsigned short*)d_ws;
  unsigned short* Wbf = Xbf + (size_t)M_TOT * K_D;
  float* hterm = (float*)(Wbf + (size_t)N_D * K_D);

  prep_kernel<<<PREP_GRID, 256, 0, stream>>>(X, Xbf, W, Wbf, hs, Hm, hterm);
  gemm_tanh<<<(M_TOT / BM) * (N_D / BN), 512, 0, stream>>>(Xbf, Wbf, hterm,
                                                           out0, out1);
}

// Round 16
// 139.881 us; speedup vs baseline: 1.2900x; 1.0687x over previous
//
#include <hip/hip_runtime.h>

// RNN_53214644797476: out = tanh(X @ W^T + hs @ H^T), hs never updated.
// => one GEMM [32768,1024]x[1024,1024]^T + tiny h_term + tanh epilogue.
// Round 16: R15 verbatim EXCEPT the epilogue: each wave transposes its
// 64x64 f32 output tile through a private 4 KB LDS region (XOR-swizzled,
// balanced banks) so nt stores become full-line dwordx4 per row
// (R15's nt column-stores caused 1.43x write amplification: WRITE_SIZE
// 131->187 MB from 64B half-line write-through).
// GEMM structure (measured best): 256x128 tile, 512 thr, 8 waves 64x64,
// BK=32, 3-buffer 2-deep counted vmcnt, 72 KB LDS, pre-swizzled inputs,
// XCD-bijective swizzle, nt prep loads + nt output stores.

typedef __bf16 bf16x8 __attribute__((ext_vector_type(8)));
typedef float f32x4 __attribute__((ext_vector_type(4)));
typedef unsigned short us8 __attribute__((ext_vector_type(8)));

constexpr int M_TOT = 32768;  // SEQ*BATCH
constexpr int K_D = 1024;
constexpr int N_D = 1024;
constexpr int BM = 256, BN = 128, BKT = 32;
constexpr int NTK = K_D / BKT;  // 32 K-tiles
constexpr int ATILE = BM * BKT; // 8192 ushorts = 16 KiB
constexpr int BTILE = BN * BKT; // 4096 ushorts = 8 KiB

__device__ __forceinline__ void async16(const void* g, void* l) {
  __builtin_amdgcn_global_load_lds(
      (const __attribute__((address_space(1))) unsigned int*)g,
      (__attribute__((address_space(3))) unsigned int*)l, 16, 0, 0);
}

__device__ __forceinline__ unsigned short f2bf(float f) {
  unsigned int u = __float_as_uint(f);
  u += 0x7FFFu + ((u >> 16) & 1u);  // round-to-nearest-even
  return (unsigned short)(u >> 16);
}

// ---- merged prep (identical to R14/R15) ----
// blocks [0, XBLK): X cvt, one 16B slot per thread (2 float4 nt-loads);
// [XBLK,+WBLK): W cvt, same; [XBLK+WBLK,+HBLK): h_term, one block per h.
// Slot pre-swizzle (matches gemm read XOR): 16B slot st of row stored at
// sd = (st&~3) | ((st&3) ^ ((row>>1)&3)).
constexpr int PREP_XBLK = M_TOT * K_D / 8 / 256;  // 16384
constexpr int PREP_WBLK = N_D * K_D / 8 / 256;    // 512
constexpr int PREP_HBLK = 1024;
constexpr int PREP_GRID = PREP_XBLK + PREP_WBLK + PREP_HBLK;

__global__ __launch_bounds__(256) void prep_kernel(
    const float* __restrict__ X, unsigned short* __restrict__ Xbf,
    const float* __restrict__ W, unsigned short* __restrict__ Wbf,
    const float* __restrict__ hs, const float* __restrict__ Hm,
    float* __restrict__ ht) {
  __shared__ float4 Hrow4[256];
  const int b = blockIdx.x;
  const int tid = threadIdx.x;

  if (b < PREP_XBLK + PREP_WBLK) {
    const float* in = (b < PREP_XBLK) ? X : W;
    unsigned short* out = (b < PREP_XBLK) ? Xbf : Wbf;
    int j = (b < PREP_XBLK) ? (b * 256 + tid) : ((b - PREP_XBLK) * 256 + tid);
    // j indexes full 16B slots (8 floats each).
    int row = j >> 7, st = j & 127;
    int sd = (st & ~3) | ((st & 3) ^ ((row >> 1) & 3));
    const f32x4* p = reinterpret_cast<const f32x4*>(in + (size_t)j * 8);
    f32x4 a = __builtin_nontemporal_load(p);      // read-once stream: nt
    f32x4 c = __builtin_nontemporal_load(p + 1);  // 2 independent loads
    us8 v;
    v[0] = f2bf(a[0]); v[1] = f2bf(a[1]); v[2] = f2bf(a[2]); v[3] = f2bf(a[3]);
    v[4] = f2bf(c[0]); v[5] = f2bf(c[1]); v[6] = f2bf(c[2]); v[7] = f2bf(c[3]);
    *reinterpret_cast<us8*>(out + (size_t)row * 1024 + sd * 8) = v;
  } else {
    // h_term[bb][h] = sum_k hs[bb][k] * Hm[h][k]
    int h = b - (PREP_XBLK + PREP_WBLK);
    Hrow4[tid] = reinterpret_cast<const float4*>(Hm + (size_t)h * 1024)[tid];
    __syncthreads();
    int w = tid >> 6, l = tid & 63;
#pragma unroll 2
    for (int bb = w * 16; bb < w * 16 + 16; ++bb) {
      const float4* hb4 = reinterpret_cast<const float4*>(hs + (size_t)bb * 1024);
      float s = 0.f;
#pragma unroll
      for (int p = 0; p < 4; ++p) {
        float4 x = hb4[l + p * 64];
        float4 y = Hrow4[l + p * 64];
        s += x.x * y.x + x.y * y.y + x.z * y.z + x.w * y.w;
      }
#pragma unroll
      for (int off = 32; off > 0; off >>= 1) s += __shfl_down(s, off, 64);
      if (l == 0) ht[bb * 1024 + h] = s;
    }
  }
}

// ---- main GEMM: C = tanh(A.B^T + ht[m%64][n]) ----
// 256x128 tile, 8 waves (4x2) of 64x64, 3-buffer 2-deep counted-vmcnt.
// Epilogue: per-wave LDS transpose -> full-line nt dwordx4 stores.
__global__ __launch_bounds__(512, 4) void gemm_tanh(
    const unsigned short* __restrict__ A, const unsigned short* __restrict__ B,
    const float* __restrict__ ht, float* __restrict__ out0,
    float* __restrict__ out1) {
  __shared__ unsigned short As[3][ATILE];  // 48 KiB
  __shared__ unsigned short Bs[3][BTILE];  // 24 KiB

  // XCD-bijective swizzle (nwg = 1024 % 8 == 0); A-panel sharers co-XCD.
  int bid = blockIdx.x;
  int swz = (bid & 7) * 128 + (bid >> 3);
  int bm = swz >> 3;  // 0..127
  int bn = swz & 7;   // 0..7

  int tid = threadIdx.x;
  int lane = tid & 63, wid = tid >> 6;
  int wr = wid >> 1, wc = wid & 1;  // 4 x 2 waves, each 64x64 output
  int fr = lane & 15, kq = lane >> 4;

  // Staging: A = 1024 chunks (256 rows x 4 slots), B = 512 chunks.
  // Thread t stages A chunks t, t+512 and B chunk t. LDS dest linear;
  // global source pre-swizzled, so source addrs are linear too.
  int c1 = tid + 512;
  const unsigned short* gA0 =
      A + (size_t)(bm * BM + (tid >> 2)) * 1024 + (tid & 3) * 8;
  const unsigned short* gA1 =
      A + (size_t)(bm * BM + (c1 >> 2)) * 1024 + (tid & 3) * 8;
  const unsigned short* gB0 =
      B + (size_t)(bn * BN + (tid >> 2)) * 1024 + (tid & 3) * 8;

  f32x4 acc[4][4] = {};

#define STAGE(kt, buf)                                  \
  {                                                     \
    async16(gA0 + (kt) * BKT, &As[buf][tid * 8]);       \
    async16(gA1 + (kt) * BKT, &As[buf][c1 * 8]);        \
    async16(gB0 + (kt) * BKT, &Bs[buf][tid * 8]);       \
  }

  // Prologue: stage tiles 0 and 1; wait tile 0 only (counted); barrier.
  STAGE(0, 0);
  STAGE(1, 1);
  asm volatile("s_waitcnt vmcnt(3)" ::: "memory");
  __builtin_amdgcn_s_barrier();
  asm volatile("" ::: "memory");

  for (int kt = 0; kt < NTK; ++kt) {
    const int cur = kt % 3;
    // Stage 2 K-steps ahead; these loads fly across this iter's barrier.
    if (kt + 2 < NTK) STAGE(kt + 2, (kt + 2) % 3);

    bf16x8 af[4], bg[4];
#pragma unroll
    for (int mi = 0; mi < 4; ++mi) {
      int ra = wr * 64 + mi * 16 + fr;
      af[mi] = *reinterpret_cast<const bf16x8*>(
          &As[cur][ra * BKT + (kq ^ ((ra >> 1) & 3)) * 8]);
    }
#pragma unroll
    for (int ni = 0; ni < 4; ++ni) {
      int rb = wc * 64 + ni * 16 + fr;
      bg[ni] = *reinterpret_cast<const bf16x8*>(
          &Bs[cur][rb * BKT + (kq ^ ((rb >> 1) & 3)) * 8]);
    }
    __builtin_amdgcn_s_setprio(1);
#pragma unroll
    for (int mi = 0; mi < 4; ++mi)
#pragma unroll
      for (int ni = 0; ni < 4; ++ni)
        acc[mi][ni] = __builtin_amdgcn_mfma_f32_16x16x32_bf16(
            af[mi], bg[ni], acc[mi][ni], 0, 0, 0);
    __builtin_amdgcn_s_setprio(0);

    if (kt + 1 < NTK) {
      // Counted drain: ensure kt+1 resident (its 3 loads are the oldest),
      // keep kt+2's 3 loads in flight across the barrier.
      if (kt + 2 < NTK)
        asm volatile("s_waitcnt vmcnt(3)" ::: "memory");
      else
        asm volatile("s_waitcnt vmcnt(0)" ::: "memory");
      __builtin_amdgcn_s_barrier();
      asm volatile("" ::: "memory");
    }
  }

  // ---- Epilogue: per-wave LDS transpose -> full-line nt stores ----
  // All waves done reading As/Bs before we reuse the LDS.
  __builtin_amdgcn_s_barrier();

  // Private 4 KB (1024 f32) region per wave inside As (8 x 4 KB = 32 KB).
  float* eps = reinterpret_cast<float*>(&As[0][0]) + wid * 1024;
  const int nbase = bn * BN + wc * 64;
  const int mwave = bm * BM + wr * 64;

#pragma unroll
  for (int mi = 0; mi < 4; ++mi) {
    // 1. compute y, scatter into LDS transposed+swizzled.
    //    row_rel = kq*4+r (0..15); logical col = ni*16+fr (0..63);
    //    stored col = colw ^ (kq*8) ^ (r*4)  [balanced banks, see notes]
#pragma unroll
    for (int r = 0; r < 4; ++r) {
      int row_rel = kq * 4 + r;
#pragma unroll
      for (int ni = 0; ni < 4; ++ni) {
        int n = nbase + ni * 16 + fr;
        float x = acc[mi][ni][r] + ht[(mi * 16 + row_rel) * 1024 + n];
        float e = __expf(2.0f * x);
        float y = 1.0f - 2.0f / (e + 1.0f);  // tanh(x), safe at +-inf
        int colws = (ni * 16 + fr) ^ (kq * 8) ^ (r * 4);
        eps[row_rel * 64 + colws] = y;
      }
    }
    // 2. gather 4 rows per b128 read (same-key XOR), nt-store full float4s.
    //    lane: row = (lane&3)+4i, logical cols 4*(lane>>2)..+3;
    //    key(row) = (row>>2)*8 ^ (row&3)*4 = i*8 ^ (lane&3)*4.
#pragma unroll
    for (int i = 0; i < 4; ++i) {
      int rrel = (lane & 3) + 4 * i;
      int colw = 4 * (lane >> 2);
      int colws = colw ^ (i * 8) ^ ((lane & 3) * 4);
      f32x4 v4 = *reinterpret_cast<const f32x4*>(&eps[rrel * 64 + colws]);
      size_t m = (size_t)mwave + mi * 16 + rrel;
      int n = nbase + colw;
      __builtin_nontemporal_store(
          v4, reinterpret_cast<f32x4*>(&out0[m * 1024 + n]));
      if (m >= (size_t)(M_TOT - 64))
        __builtin_nontemporal_store(
            v4, reinterpret_cast<f32x4*>(&out1[(m - (M_TOT - 64)) * 1024 + n]));
    }
  }
#undef STAGE
}

extern "C" void kernel_launch(void* const* d_in, const int* in_sizes, int n_in,
                              void* d_out, int out_size, void* d_ws,
                              size_t ws_size, hipStream_t stream) {
  (void)in_sizes; (void)n_in; (void)out_size; (void)ws_size;
  const float* X  = (const float*)d_in[0];  // [512,64,1024] = [32768,1024]
  const float* hs = (const float*)d_in[1];  // [64,1024]
  const float* W  = (const float*)d_in[2];  // [1024,1024]
  const float* Hm = (const float*)d_in[3];  // [1024,1024]
  float* out0 = (float*)d_out;               // [32768,1024]
  float* out1 = out0 + (size_t)M_TOT * N_D;  // [64,1024]

  // ws layout: Xbf (64 MiB) | Wbf (2 MiB) | hterm (256 KiB)
  unsigned short* Xbf = (unsigned short*)d_ws;
  unsigned short* Wbf = Xbf + (size_t)M_TOT * K_D;
  float* hterm = (float*)(Wbf + (size_t)N_D * K_D);

  prep_kernel<<<PREP_GRID, 256, 0, stream>>>(X, Xbf, W, Wbf, hs, Hm, hterm);
  gemm_tanh<<<(M_TOT / BM) * (N_D / BN), 512, 0, stream>>>(Xbf, Wbf, hterm,
                                                           out0, out1);
}